// Round 1
// baseline (540.431 us; speedup 1.0000x reference)
//
#include <hip/hip_runtime.h>

// Problem constants (fixed by setup_inputs: B=32, N=1024, D=1024, K=512).
constexpr int Bb = 32;
constexpr int Nn = 1024;
constexpr int Dd = 1024;
constexpr int Kk = 512;            // number of updated rows per batch
constexpr int Mm = Bb * Kk;        // 16384 GEMM rows
constexpr int KD = 2 * Dd;         // 2048 fused GEMM K-dim ([h|w] x [U|V]^T)

using bf16x8 = __bf16 __attribute__((ext_vector_type(8)));
using f32x4  = float __attribute__((ext_vector_type(4)));

// ---------------------------------------------------------------------------
// Workspace layout (total ~4.5 MB; safe for any reasonable ws_size):
//   [0, 4 MiB)           Bbf : bf16 [1024][2048]  = [U | V] rows
//   +4 MiB               g   : f32  [16384]
//   +4 MiB+64K           sW  : f32  [32][1024]
//   +4 MiB+192K          rownorm : f32 [16384]  (atomic sum of squares)
// ---------------------------------------------------------------------------
constexpr size_t WS_BBF = 0;
constexpr size_t WS_G   = (size_t)4 * 1024 * 1024;
constexpr size_t WS_SW  = WS_G + 64 * 1024;
constexpr size_t WS_RN  = WS_SW + 128 * 1024;

// --- pack [U|V] into bf16 ws matrix Bbf[e][0:1024]=U[e,:], [1024:2048]=V[e,:]
__global__ void prep_b_kernel(const float* __restrict__ U,
                              const float* __restrict__ V,
                              __bf16* __restrict__ Bbf) {
  int t = blockIdx.x * 256 + threadIdx.x;       // 262144 threads, 8 elems each
  int e = t >> 8;
  int c = (t & 255) << 3;                        // col in [0,2048)
  const float* src = (c < Dd) ? (U + (size_t)e * Dd + c)
                              : (V + (size_t)e * Dd + (c - Dd));
  f32x4 f0 = *(const f32x4*)src;
  f32x4 f1 = *(const f32x4*)(src + 4);
  bf16x8 v;
  v[0] = (__bf16)f0[0]; v[1] = (__bf16)f0[1]; v[2] = (__bf16)f0[2]; v[3] = (__bf16)f0[3];
  v[4] = (__bf16)f1[0]; v[5] = (__bf16)f1[1]; v[6] = (__bf16)f1[2]; v[7] = (__bf16)f1[3];
  *(bf16x8*)(Bbf + (size_t)e * KD + c) = v;
}

// --- sW[b][e] = sum_d s[b,d] * W[e,d]   (fp32, one wave per e)
__global__ void sw_kernel(const float* __restrict__ s,
                          const float* __restrict__ W,
                          float* __restrict__ sW) {
  int e = blockIdx.x * 4 + (threadIdx.x >> 6);
  int lane = threadIdx.x & 63;
  const float* wp = W + (size_t)e * Dd;
  float wr[16];
#pragma unroll
  for (int c = 0; c < 4; c++) {
    f32x4 wv = *(const f32x4*)(wp + c * 256 + lane * 4);
    wr[c*4+0] = wv[0]; wr[c*4+1] = wv[1]; wr[c*4+2] = wv[2]; wr[c*4+3] = wv[3];
  }
  for (int b = 0; b < Bb; b++) {
    const float* sp = s + (size_t)b * Dd;
    float acc = 0.f;
#pragma unroll
    for (int c = 0; c < 4; c++) {
      f32x4 sv = *(const f32x4*)(sp + c * 256 + lane * 4);
      acc += sv[0]*wr[c*4+0] + sv[1]*wr[c*4+1] + sv[2]*wr[c*4+2] + sv[3]*wr[c*4+3];
    }
#pragma unroll
    for (int off = 32; off; off >>= 1) acc += __shfl_xor(acc, off);
    if (lane == 0) sW[b * Nn + e] = acc;
  }
}

// --- g[m] = sigmoid( s[b,:] . (h[b,k,:]+w[b,k,:]) )  fp32, one wave per row
__global__ void g_kernel(const float* __restrict__ s,
                         const float* __restrict__ hiddens,
                         const float* __restrict__ keys,
                         const int* __restrict__ idx,
                         float* __restrict__ g) {
  int wid = blockIdx.x * 4 + (threadIdx.x >> 6);   // row m in [0, Mm)
  int lane = threadIdx.x & 63;
  int b = wid >> 9;                                 // /Kk
  int k = wid & (Kk - 1);
  int row = idx[k];
  const float* hp = hiddens + ((size_t)(b * Nn + row)) * Dd;
  const float* wp = keys    + ((size_t)(b * Nn + row)) * Dd;
  const float* sp = s + (size_t)b * Dd;
  float acc = 0.f;
#pragma unroll
  for (int c = 0; c < 4; c++) {
    int d = c * 256 + lane * 4;
    f32x4 hv = *(const f32x4*)(hp + d);
    f32x4 wv = *(const f32x4*)(wp + d);
    f32x4 sv = *(const f32x4*)(sp + d);
    acc += sv[0]*(hv[0]+wv[0]) + sv[1]*(hv[1]+wv[1])
         + sv[2]*(hv[2]+wv[2]) + sv[3]*(hv[3]+wv[3]);
  }
#pragma unroll
  for (int off = 32; off; off >>= 1) acc += __shfl_xor(acc, off);
  if (lane == 0) g[wid] = 1.f / (1.f + expf(-acc));
}

// --- main fused GEMM: C[m][e] = relu( A[m,:].B[e,:] + sW[b,e] ),
//     out[b, idx[k], e] = h + g*C ; rownorm[m] += partial sum of squares
//     A row m = [ hiddens[b, idx[k], :] | keys[b, idx[k], :] ] converted bf16
__global__ __launch_bounds__(256)
void gemm_kernel(const float* __restrict__ hiddens,
                 const float* __restrict__ keys,
                 const int* __restrict__ idx,
                 const __bf16* __restrict__ Bbf,
                 const float* __restrict__ sW,
                 const float* __restrict__ g,
                 float* __restrict__ rownorm,
                 float* __restrict__ out) {
  __shared__ __bf16 a_lds[128 * 64];
  __shared__ __bf16 b_lds[128 * 64];

  int bid = blockIdx.x;
  int mt = bid >> 3;            // 128 M-tiles
  int nt = bid & 7;             // 8 N-tiles
  int m0 = mt * 128, e0 = nt * 128;
  int tid = threadIdx.x, lane = tid & 63, wave = tid >> 6;

  // Per-thread A staging assignment: 4 pairs of (row, 8-float chunk).
  size_t roff[4]; int prow[4], pcol[4];
#pragma unroll
  for (int i = 0; i < 4; i++) {
    int p = tid + i * 256;       // 0..1023
    int row = p >> 3;            // 0..127
    pcol[i] = (p & 7) * 8;       // 0..56
    prow[i] = row;
    int m = m0 + row;
    int b = m >> 9;
    int r = idx[m & (Kk - 1)];
    roff[i] = ((size_t)(b * Nn + r)) * Dd;
  }
  // Per-thread B staging (global_load_lds, 16B each, linear LDS).
  int bofs[4], brow[4], bcolb[4];
#pragma unroll
  for (int i = 0; i < 4; i++) {
    int o = (wave * 4 + i) * 1024 + lane * 16;   // byte offset in b_lds
    bofs[i] = o;
    brow[i] = o >> 7;
    bcolb[i] = o & 127;
  }

  f32x4 acc[4][4] = {};
  int wm = (wave >> 1) * 64, we = (wave & 1) * 64;
  int lr = lane & 15, lg = lane >> 4;
  const char* BbfB = (const char*)Bbf;

  for (int t = 0; t < KD / 64; ++t) {
    int kd0 = t * 64;
    const float* Asrc = (kd0 < Dd) ? hiddens : keys;
    int d0 = kd0 & (Dd - 1);

    // B tile: bf16 ws -> LDS direct (16B global_load_lds)
#pragma unroll
    for (int i = 0; i < 4; i++) {
      const void* gp = BbfB + ((size_t)(e0 + brow[i]) * KD + kd0) * 2 + bcolb[i];
      __builtin_amdgcn_global_load_lds(
          (const __attribute__((address_space(1))) void*)gp,
          (__attribute__((address_space(3))) void*)((char*)b_lds + bofs[i]),
          16, 0, 0);
    }
    // A tile: gather fp32, convert bf16, ds_write
#pragma unroll
    for (int i = 0; i < 4; i++) {
      const float* src = Asrc + roff[i] + d0 + pcol[i];
      f32x4 f0 = *(const f32x4*)src;
      f32x4 f1 = *(const f32x4*)(src + 4);
      bf16x8 v;
      v[0]=(__bf16)f0[0]; v[1]=(__bf16)f0[1]; v[2]=(__bf16)f0[2]; v[3]=(__bf16)f0[3];
      v[4]=(__bf16)f1[0]; v[5]=(__bf16)f1[1]; v[6]=(__bf16)f1[2]; v[7]=(__bf16)f1[3];
      *(bf16x8*)&a_lds[prow[i] * 64 + pcol[i]] = v;
    }
    __syncthreads();   // drains vmcnt (incl. global_load_lds) + lgkm

#pragma unroll
    for (int kh = 0; kh < 2; ++kh) {
      bf16x8 af[4], bfr[4];
#pragma unroll
      for (int i = 0; i < 4; i++)
        af[i] = *(const bf16x8*)&a_lds[(wm + i * 16 + lr) * 64 + kh * 32 + lg * 8];
#pragma unroll
      for (int j = 0; j < 4; j++)
        bfr[j] = *(const bf16x8*)&b_lds[(we + j * 16 + lr) * 64 + kh * 32 + lg * 8];
#pragma unroll
      for (int i = 0; i < 4; i++)
#pragma unroll
        for (int j = 0; j < 4; j++)
          acc[i][j] = __builtin_amdgcn_mfma_f32_16x16x32_bf16(af[i], bfr[j], acc[i][j], 0, 0, 0);
    }
    __syncthreads();
  }

  // Epilogue: bias + relu + gate + residual + scatter + norm partials.
  // C/D layout (m89): lane holds C[(lane>>4)*4 + r][lane&15] per 16x16 frag.
#pragma unroll
  for (int i = 0; i < 4; i++) {
#pragma unroll
    for (int r = 0; r < 4; r++) {
      int m = m0 + wm + i * 16 + lg * 4 + r;
      int b = m >> 9;
      int rowidx = idx[m & (Kk - 1)];
      size_t base = ((size_t)(b * Nn + rowidx)) * Dd;
      float gg = g[m];
      float part = 0.f;
#pragma unroll
      for (int j = 0; j < 4; j++) {
        int e = e0 + we + j * 16 + lr;
        float ht = acc[i][j][r] + sW[b * Nn + e];
        ht = fmaxf(ht, 0.f);
        float v = hiddens[base + e] + gg * ht;
        out[base + e] = v;
        part += v * v;
      }
      part += __shfl_xor(part, 1);
      part += __shfl_xor(part, 2);
      part += __shfl_xor(part, 4);
      part += __shfl_xor(part, 8);
      if (lr == 0) atomicAdd(&rownorm[m], part);
    }
  }
}

// --- rescale updated rows by rsqrt(max(rownorm, eps)); one block per row
__global__ void norm_kernel(const int* __restrict__ idx,
                            const float* __restrict__ rownorm,
                            float* __restrict__ out) {
  int m = blockIdx.x;
  int b = m >> 9;
  int rowidx = idx[m & (Kk - 1)];
  float nr = fmaxf(rownorm[m], 1e-12f);
  float y = rsqrtf(nr);
  y = y * (1.5f - 0.5f * nr * y * y);   // one Newton step for fp32 accuracy
  f32x4* p = (f32x4*)(out + ((size_t)(b * Nn + rowidx)) * Dd);
  f32x4 v = p[threadIdx.x];
  v[0] *= y; v[1] *= y; v[2] *= y; v[3] *= y;
  p[threadIdx.x] = v;
}

extern "C" void kernel_launch(void* const* d_in, const int* in_sizes, int n_in,
                              void* d_out, int out_size, void* d_ws, size_t ws_size,
                              hipStream_t stream) {
  const float* s       = (const float*)d_in[0];
  const float* hiddens = (const float*)d_in[1];
  const float* keys    = (const float*)d_in[2];
  const float* U       = (const float*)d_in[3];
  const float* V       = (const float*)d_in[4];
  const float* W       = (const float*)d_in[5];
  const int*   idx     = (const int*)d_in[6];
  float* out = (float*)d_out;

  char* ws = (char*)d_ws;
  __bf16* Bbf    = (__bf16*)(ws + WS_BBF);
  float*  g      = (float*)(ws + WS_G);
  float*  sW     = (float*)(ws + WS_SW);
  float*  rnorm  = (float*)(ws + WS_RN);

  // 1. out <- hiddens (rows at indices get overwritten below)
  hipMemcpyAsync(out, hiddens, (size_t)out_size * sizeof(float),
                 hipMemcpyDeviceToDevice, stream);
  // 2. zero the atomic row-norm accumulator (ws is poisoned each launch)
  hipMemsetAsync(rnorm, 0, Mm * sizeof(float), stream);
  // 3. pack [U|V] to bf16
  prep_b_kernel<<<1024, 256, 0, stream>>>(U, V, Bbf);
  // 4. fp32 bias sW = s @ W^T
  sw_kernel<<<Nn / 4, 256, 0, stream>>>(s, W, sW);
  // 5. fp32 gate g
  g_kernel<<<Mm / 4, 256, 0, stream>>>(s, hiddens, keys, idx, g);
  // 6. fused bf16 MFMA GEMM + epilogue
  gemm_kernel<<<(Mm / 128) * (Nn / 128), 256, 0, stream>>>(
      hiddens, keys, idx, Bbf, sW, g, rnorm, out);
  // 7. normalize updated rows
  norm_kernel<<<Mm, 256, 0, stream>>>(idx, rnorm, out);
}

// Round 2
// 519.449 us; speedup vs baseline: 1.0404x; 1.0404x over previous
//
#include <hip/hip_runtime.h>

// Problem constants (fixed by setup_inputs: B=32, N=1024, D=1024, K=512).
constexpr int Bb = 32;
constexpr int Nn = 1024;
constexpr int Dd = 1024;
constexpr int Kk = 512;            // number of updated rows per batch
constexpr int Mm = Bb * Kk;        // 16384 GEMM rows
constexpr int KD = 2 * Dd;         // 2048 fused GEMM K-dim ([h|w] x [U|V]^T)

using bf16x8 = __bf16 __attribute__((ext_vector_type(8)));
using f32x4  = float __attribute__((ext_vector_type(4)));

// ---------------------------------------------------------------------------
// Workspace layout (~71.6 MB):
//   [0, 64 MiB)    Abf : bf16 [16384][2048] = gathered [h | w] rows
//   +64 MiB        Bbf : bf16 [1024][2048]  = [U | V] rows        (4 MiB)
//   +68 MiB        g   : f32 [16384]                               (64 KiB)
//   ...            sW  : f32 [32][1024]                            (128 KiB)
//   ...            rownorm : f32 [16384] (atomic sum of squares)   (64 KiB)
//   ...            mask: int [1024]                                (4 KiB)
// ---------------------------------------------------------------------------
constexpr size_t WS_ABF  = 0;
constexpr size_t WS_BBF  = (size_t)Mm * KD * 2;                 // 64 MiB
constexpr size_t WS_G    = WS_BBF + (size_t)Nn * KD * 2;        // +4 MiB
constexpr size_t WS_SW   = WS_G + Mm * sizeof(float);
constexpr size_t WS_RN   = WS_SW + Bb * Nn * sizeof(float);
constexpr size_t WS_MASK = WS_RN + Mm * sizeof(float);

// --- build mask[n] = 1 iff n in indices (single block)
__global__ void mask_kernel(const int* __restrict__ idx, int* __restrict__ mask) {
  int t = threadIdx.x;
  mask[t] = 0;
  __syncthreads();
  if (t < Kk) mask[idx[t]] = 1;
}

// --- copy non-updated rows hiddens -> out (updated rows written by GEMM)
__global__ void copy_kernel(const float* __restrict__ hiddens,
                            const int* __restrict__ mask,
                            float* __restrict__ out) {
  int bid = blockIdx.x;                 // (b, n) row
  int n = bid & (Nn - 1);
  if (mask[n]) return;
  size_t base = (size_t)bid * Dd + threadIdx.x * 4;
  *(f32x4*)(out + base) = *(const f32x4*)(hiddens + base);
}

// --- pack [U|V] into bf16 ws matrix Bbf[e][0:1024]=U[e,:], [1024:2048]=V[e,:]
__global__ void prep_b_kernel(const float* __restrict__ U,
                              const float* __restrict__ V,
                              __bf16* __restrict__ Bbf) {
  int t = blockIdx.x * 256 + threadIdx.x;       // 262144 threads, 8 elems each
  int e = t >> 8;
  int c = (t & 255) << 3;                        // col in [0,2048)
  const float* src = (c < Dd) ? (U + (size_t)e * Dd + c)
                              : (V + (size_t)e * Dd + (c - Dd));
  f32x4 f0 = *(const f32x4*)src;
  f32x4 f1 = *(const f32x4*)(src + 4);
  bf16x8 v;
  v[0] = (__bf16)f0[0]; v[1] = (__bf16)f0[1]; v[2] = (__bf16)f0[2]; v[3] = (__bf16)f0[3];
  v[4] = (__bf16)f1[0]; v[5] = (__bf16)f1[1]; v[6] = (__bf16)f1[2]; v[7] = (__bf16)f1[3];
  *(bf16x8*)(Bbf + (size_t)e * KD + c) = v;
}

// --- sW[b][e] = sum_d s[b,d] * W[e,d]   (fp32, one wave per e)
__global__ void sw_kernel(const float* __restrict__ s,
                          const float* __restrict__ W,
                          float* __restrict__ sW) {
  int e = blockIdx.x * 4 + (threadIdx.x >> 6);
  int lane = threadIdx.x & 63;
  const float* wp = W + (size_t)e * Dd;
  float wr[16];
#pragma unroll
  for (int c = 0; c < 4; c++) {
    f32x4 wv = *(const f32x4*)(wp + c * 256 + lane * 4);
    wr[c*4+0] = wv[0]; wr[c*4+1] = wv[1]; wr[c*4+2] = wv[2]; wr[c*4+3] = wv[3];
  }
  for (int b = 0; b < Bb; b++) {
    const float* sp = s + (size_t)b * Dd;
    float acc = 0.f;
#pragma unroll
    for (int c = 0; c < 4; c++) {
      f32x4 sv = *(const f32x4*)(sp + c * 256 + lane * 4);
      acc += sv[0]*wr[c*4+0] + sv[1]*wr[c*4+1] + sv[2]*wr[c*4+2] + sv[3]*wr[c*4+3];
    }
#pragma unroll
    for (int off = 32; off; off >>= 1) acc += __shfl_xor(acc, off);
    if (lane == 0) sW[b * Nn + e] = acc;
  }
}

// --- fused gather: g[m] = sigmoid(s.(h+w)) in fp32, AND write bf16 A-rows
//     Abf[m][0:1024] = bf16(h[b, idx[k], :]),  [1024:2048] = bf16(w[...])
__global__ void pack_g_kernel(const float* __restrict__ s,
                              const float* __restrict__ hiddens,
                              const float* __restrict__ keys,
                              const int* __restrict__ idx,
                              __bf16* __restrict__ Abf,
                              float* __restrict__ g) {
  int m = blockIdx.x * 4 + (threadIdx.x >> 6);     // row m in [0, Mm)
  int lane = threadIdx.x & 63;
  int b = m >> 9;                                   // / Kk
  int k = m & (Kk - 1);
  int row = idx[k];
  const float* hp = hiddens + ((size_t)(b * Nn + row)) * Dd;
  const float* wp = keys    + ((size_t)(b * Nn + row)) * Dd;
  const float* sp = s + (size_t)b * Dd;
  __bf16* ap = Abf + (size_t)m * KD;

  float acc = 0.f;
#pragma unroll
  for (int c = 0; c < 2; c++) {
    int d = c * 512 + lane * 8;
    f32x4 h0 = *(const f32x4*)(hp + d);
    f32x4 h1 = *(const f32x4*)(hp + d + 4);
    f32x4 w0 = *(const f32x4*)(wp + d);
    f32x4 w1 = *(const f32x4*)(wp + d + 4);
    f32x4 s0 = *(const f32x4*)(sp + d);
    f32x4 s1 = *(const f32x4*)(sp + d + 4);
    acc += s0[0]*(h0[0]+w0[0]) + s0[1]*(h0[1]+w0[1])
         + s0[2]*(h0[2]+w0[2]) + s0[3]*(h0[3]+w0[3])
         + s1[0]*(h1[0]+w1[0]) + s1[1]*(h1[1]+w1[1])
         + s1[2]*(h1[2]+w1[2]) + s1[3]*(h1[3]+w1[3]);
    bf16x8 hv, wv;
    hv[0]=(__bf16)h0[0]; hv[1]=(__bf16)h0[1]; hv[2]=(__bf16)h0[2]; hv[3]=(__bf16)h0[3];
    hv[4]=(__bf16)h1[0]; hv[5]=(__bf16)h1[1]; hv[6]=(__bf16)h1[2]; hv[7]=(__bf16)h1[3];
    wv[0]=(__bf16)w0[0]; wv[1]=(__bf16)w0[1]; wv[2]=(__bf16)w0[2]; wv[3]=(__bf16)w0[3];
    wv[4]=(__bf16)w1[0]; wv[5]=(__bf16)w1[1]; wv[6]=(__bf16)w1[2]; wv[7]=(__bf16)w1[3];
    *(bf16x8*)(ap + d) = hv;
    *(bf16x8*)(ap + Dd + d) = wv;
  }
#pragma unroll
  for (int off = 32; off; off >>= 1) acc += __shfl_xor(acc, off);
  if (lane == 0) g[m] = 1.f / (1.f + expf(-acc));
}

// --- main fused GEMM (m97 structure: both operands via global_load_lds):
//     C[m][e] = relu( Abf[m,:].Bbf[e,:] + sW[b,e] )
//     out[b, idx[k], e] = h + g*C ; rownorm[m] += partial sum of squares
__global__ __launch_bounds__(256)
void gemm_kernel(const __bf16* __restrict__ Abf,
                 const __bf16* __restrict__ Bbf,
                 const int* __restrict__ idx,
                 const float* __restrict__ sW,
                 const float* __restrict__ g,
                 const float* __restrict__ hiddens,
                 float* __restrict__ rownorm,
                 float* __restrict__ out) {
  __shared__ __bf16 a_lds[128 * 64];
  __shared__ __bf16 b_lds[128 * 64];

  int bid = blockIdx.x;
  // Same-A-panel blocks co-locate on one XCD: XCD = bid%8 = mt%8.
  int mt = bid & 127;           // 128 M-tiles
  int nt = bid >> 7;            // 8 N-tiles
  int m0 = mt * 128, e0 = nt * 128;
  int tid = threadIdx.x, lane = tid & 63, wave = tid >> 6;

  // Staging: 4 chunks of 16B per thread per operand, linear LDS.
  int lofs[4]; size_t aoff[4], boff[4];
#pragma unroll
  for (int i = 0; i < 4; i++) {
    int o = (wave * 4 + i) * 1024 + lane * 16;   // LDS byte offset
    lofs[i] = o;
    int row = o >> 7;                             // tile row 0..127
    int colb = o & 127;                           // byte col (64 bf16 = 128B)
    aoff[i] = ((size_t)(m0 + row) * KD) * 2 + colb;
    boff[i] = ((size_t)(e0 + row) * KD) * 2 + colb;
  }

  f32x4 acc[4][4] = {};
  int wm = (wave >> 1) * 64, we = (wave & 1) * 64;
  int lr = lane & 15, lg = lane >> 4;
  const char* Ab = (const char*)Abf;
  const char* Bbp = (const char*)Bbf;

  for (int t = 0; t < KD / 64; ++t) {
    size_t kb = (size_t)t * 128;                  // kd0*2 bytes
#pragma unroll
    for (int i = 0; i < 4; i++) {
      __builtin_amdgcn_global_load_lds(
          (const __attribute__((address_space(1))) void*)(Ab + aoff[i] + kb),
          (__attribute__((address_space(3))) void*)((char*)a_lds + lofs[i]),
          16, 0, 0);
      __builtin_amdgcn_global_load_lds(
          (const __attribute__((address_space(1))) void*)(Bbp + boff[i] + kb),
          (__attribute__((address_space(3))) void*)((char*)b_lds + lofs[i]),
          16, 0, 0);
    }
    __syncthreads();   // drains vmcnt (incl. global_load_lds)

#pragma unroll
    for (int kh = 0; kh < 2; ++kh) {
      bf16x8 af[4], bfr[4];
#pragma unroll
      for (int i = 0; i < 4; i++)
        af[i] = *(const bf16x8*)&a_lds[(wm + i * 16 + lr) * 64 + kh * 32 + lg * 8];
#pragma unroll
      for (int j = 0; j < 4; j++)
        bfr[j] = *(const bf16x8*)&b_lds[(we + j * 16 + lr) * 64 + kh * 32 + lg * 8];
#pragma unroll
      for (int i = 0; i < 4; i++)
#pragma unroll
        for (int j = 0; j < 4; j++)
          acc[i][j] = __builtin_amdgcn_mfma_f32_16x16x32_bf16(af[i], bfr[j], acc[i][j], 0, 0, 0);
    }
    __syncthreads();
  }

  // Epilogue: bias + relu + gate + residual + scatter + norm partials.
  // C/D layout (m89): lane holds C[(lane>>4)*4 + r][lane&15] per 16x16 frag.
#pragma unroll
  for (int i = 0; i < 4; i++) {
#pragma unroll
    for (int r = 0; r < 4; r++) {
      int m = m0 + wm + i * 16 + lg * 4 + r;
      int b = m >> 9;
      int rowidx = idx[m & (Kk - 1)];
      size_t base = ((size_t)(b * Nn + rowidx)) * Dd;
      float gg = g[m];
      float part = 0.f;
#pragma unroll
      for (int j = 0; j < 4; j++) {
        int e = e0 + we + j * 16 + lr;
        float ht = acc[i][j][r] + sW[b * Nn + e];
        ht = fmaxf(ht, 0.f);
        float v = hiddens[base + e] + gg * ht;
        out[base + e] = v;
        part += v * v;
      }
      part += __shfl_xor(part, 1);
      part += __shfl_xor(part, 2);
      part += __shfl_xor(part, 4);
      part += __shfl_xor(part, 8);
      if (lr == 0) atomicAdd(&rownorm[m], part);
    }
  }
}

// --- rescale updated rows by rsqrt(max(rownorm, eps)); one block per row
__global__ void norm_kernel(const int* __restrict__ idx,
                            const float* __restrict__ rownorm,
                            float* __restrict__ out) {
  int m = blockIdx.x;
  int b = m >> 9;
  int rowidx = idx[m & (Kk - 1)];
  float nr = fmaxf(rownorm[m], 1e-12f);
  float y = rsqrtf(nr);
  y = y * (1.5f - 0.5f * nr * y * y);   // one Newton step for fp32 accuracy
  f32x4* p = (f32x4*)(out + ((size_t)(b * Nn + rowidx)) * Dd);
  f32x4 v = p[threadIdx.x];
  v[0] *= y; v[1] *= y; v[2] *= y; v[3] *= y;
  p[threadIdx.x] = v;
}

extern "C" void kernel_launch(void* const* d_in, const int* in_sizes, int n_in,
                              void* d_out, int out_size, void* d_ws, size_t ws_size,
                              hipStream_t stream) {
  const float* s       = (const float*)d_in[0];
  const float* hiddens = (const float*)d_in[1];
  const float* keys    = (const float*)d_in[2];
  const float* U       = (const float*)d_in[3];
  const float* V       = (const float*)d_in[4];
  const float* W       = (const float*)d_in[5];
  const int*   idx     = (const int*)d_in[6];
  float* out = (float*)d_out;

  char* ws = (char*)d_ws;
  __bf16* Abf   = (__bf16*)(ws + WS_ABF);
  __bf16* Bbf   = (__bf16*)(ws + WS_BBF);
  float*  g     = (float*)(ws + WS_G);
  float*  sW    = (float*)(ws + WS_SW);
  float*  rnorm = (float*)(ws + WS_RN);
  int*    mask  = (int*)(ws + WS_MASK);

  // zero the atomic row-norm accumulator (ws is re-poisoned each launch)
  hipMemsetAsync(rnorm, 0, Mm * sizeof(float), stream);
  // updated-row mask, then copy only non-updated rows
  mask_kernel<<<1, Nn, 0, stream>>>(idx, mask);
  copy_kernel<<<Bb * Nn, 256, 0, stream>>>(hiddens, mask, out);
  // pack [U|V] to bf16
  prep_b_kernel<<<1024, 256, 0, stream>>>(U, V, Bbf);
  // fp32 bias sW = s @ W^T
  sw_kernel<<<Nn / 4, 256, 0, stream>>>(s, W, sW);
  // fused gather + bf16 pack + fp32 gate
  pack_g_kernel<<<Mm / 4, 256, 0, stream>>>(s, hiddens, keys, idx, Abf, g);
  // fused bf16 MFMA GEMM + epilogue
  gemm_kernel<<<(Mm / 128) * (Nn / 128), 256, 0, stream>>>(
      Abf, Bbf, idx, sW, g, hiddens, rnorm, out);
  // normalize updated rows
  norm_kernel<<<Mm, 256, 0, stream>>>(idx, rnorm, out);
}

// Round 3
// 486.166 us; speedup vs baseline: 1.1116x; 1.0685x over previous
//
#include <hip/hip_runtime.h>

// Problem constants (fixed by setup_inputs: B=32, N=1024, D=1024, K=512).
constexpr int Bb = 32;
constexpr int Nn = 1024;
constexpr int Dd = 1024;
constexpr int Kk = 512;            // updated rows per batch
constexpr int Mm = Bb * Kk;        // 16384 GEMM rows
constexpr int KD = 2 * Dd;         // 2048 fused K-dim ([h|w] x [U|V]^T)
constexpr int NT = KD / 64;        // 32 K-tiles of BK=64

using bf16x8 = __bf16 __attribute__((ext_vector_type(8)));
using f32x4  = float __attribute__((ext_vector_type(4)));

// ---------------------------------------------------------------------------
// Workspace layout (~68.3 MB):
//   [0, 64 MiB)    Abf : bf16 [16384][2048] = gathered [h | w] rows
//   +64 MiB        Bbf : bf16 [1024][2048]  = [U | V] rows        (4 MiB)
//   then g[16384], sW[32][1024], rownorm[16384], mask[1024]
// ---------------------------------------------------------------------------
constexpr size_t WS_ABF  = 0;
constexpr size_t WS_BBF  = (size_t)Mm * KD * 2;
constexpr size_t WS_G    = WS_BBF + (size_t)Nn * KD * 2;
constexpr size_t WS_SW   = WS_G + Mm * sizeof(float);
constexpr size_t WS_RN   = WS_SW + Bb * Nn * sizeof(float);
constexpr size_t WS_MASK = WS_RN + Mm * sizeof(float);

// --- mask[n] = k+1 iff idx[k]==n else 0 (single block)
__global__ void mask_kernel(const int* __restrict__ idx, int* __restrict__ mask) {
  int t = threadIdx.x;
  mask[t] = 0;
  __syncthreads();
  if (t < Kk) mask[idx[t]] = t + 1;
}

// --- pack [U|V] into bf16 Bbf[e][0:1024]=U[e,:], [1024:2048]=V[e,:]
__global__ void prep_b_kernel(const float* __restrict__ U,
                              const float* __restrict__ V,
                              __bf16* __restrict__ Bbf) {
  int t = blockIdx.x * 256 + threadIdx.x;
  int e = t >> 8;
  int c = (t & 255) << 3;
  const float* src = (c < Dd) ? (U + (size_t)e * Dd + c)
                              : (V + (size_t)e * Dd + (c - Dd));
  f32x4 f0 = *(const f32x4*)src;
  f32x4 f1 = *(const f32x4*)(src + 4);
  bf16x8 v;
  v[0]=(__bf16)f0[0]; v[1]=(__bf16)f0[1]; v[2]=(__bf16)f0[2]; v[3]=(__bf16)f0[3];
  v[4]=(__bf16)f1[0]; v[5]=(__bf16)f1[1]; v[6]=(__bf16)f1[2]; v[7]=(__bf16)f1[3];
  *(bf16x8*)(Bbf + (size_t)e * KD + c) = v;
}

// --- sW[b][e] = sum_d s[b,d] * W[e,d]
__global__ void sw_kernel(const float* __restrict__ s,
                          const float* __restrict__ W,
                          float* __restrict__ sW) {
  int e = blockIdx.x * 4 + (threadIdx.x >> 6);
  int lane = threadIdx.x & 63;
  const float* wp = W + (size_t)e * Dd;
  float wr[16];
#pragma unroll
  for (int c = 0; c < 4; c++) {
    f32x4 wv = *(const f32x4*)(wp + c * 256 + lane * 4);
    wr[c*4+0]=wv[0]; wr[c*4+1]=wv[1]; wr[c*4+2]=wv[2]; wr[c*4+3]=wv[3];
  }
  for (int b = 0; b < Bb; b++) {
    const float* sp = s + (size_t)b * Dd;
    float acc = 0.f;
#pragma unroll
    for (int c = 0; c < 4; c++) {
      f32x4 sv = *(const f32x4*)(sp + c * 256 + lane * 4);
      acc += sv[0]*wr[c*4+0] + sv[1]*wr[c*4+1] + sv[2]*wr[c*4+2] + sv[3]*wr[c*4+3];
    }
#pragma unroll
    for (int off = 32; off; off >>= 1) acc += __shfl_xor(acc, off);
    if (lane == 0) sW[b * Nn + e] = acc;
  }
}

// --- fused per-row kernel: copy non-updated rows; for updated rows pack
//     bf16 [h|w] into Abf AND compute g = sigmoid(s.(h+w)) in fp32.
__global__ __launch_bounds__(256)
void prep_rows_kernel(const float* __restrict__ s,
                      const float* __restrict__ hiddens,
                      const float* __restrict__ keys,
                      const int* __restrict__ mask,
                      __bf16* __restrict__ Abf,
                      float* __restrict__ g_out,
                      float* __restrict__ out) {
  __shared__ float red[4];
  int bid = blockIdx.x;                 // (b, n)
  int b = bid >> 10, n = bid & 1023;
  int tid = threadIdx.x;
  int mk = mask[n];
  const float* hp = hiddens + (size_t)bid * Dd;
  if (mk == 0) {                        // plain copy (uniform per block)
    ((f32x4*)(out + (size_t)bid * Dd))[tid] = ((const f32x4*)hp)[tid];
    return;
  }
  int m = b * Kk + (mk - 1);
  const float* src = (tid < 128) ? hp : (keys + (size_t)bid * Dd);
  int d = (tid & 127) * 8;
  const float* sp = s + (size_t)b * Dd + d;
  f32x4 x0 = *(const f32x4*)(src + d);
  f32x4 x1 = *(const f32x4*)(src + d + 4);
  f32x4 s0 = *(const f32x4*)sp;
  f32x4 s1 = *(const f32x4*)(sp + 4);
  float part = s0[0]*x0[0]+s0[1]*x0[1]+s0[2]*x0[2]+s0[3]*x0[3]
             + s1[0]*x1[0]+s1[1]*x1[1]+s1[2]*x1[2]+s1[3]*x1[3];
  bf16x8 v;
  v[0]=(__bf16)x0[0]; v[1]=(__bf16)x0[1]; v[2]=(__bf16)x0[2]; v[3]=(__bf16)x0[3];
  v[4]=(__bf16)x1[0]; v[5]=(__bf16)x1[1]; v[6]=(__bf16)x1[2]; v[7]=(__bf16)x1[3];
  *(bf16x8*)(Abf + (size_t)m * KD + (tid < 128 ? 0 : Dd) + d) = v;
#pragma unroll
  for (int off = 32; off; off >>= 1) part += __shfl_xor(part, off);
  if ((tid & 63) == 0) red[tid >> 6] = part;
  __syncthreads();
  if (tid == 0) {
    float acc = red[0] + red[1] + red[2] + red[3];
    g_out[m] = 1.f / (1.f + expf(-acc));
  }
}

// ---------------------------------------------------------------------------
// 256x256 8-phase GEMM (T2 st-swizzle + T3/T4 counted vmcnt + T5 setprio).
// LDS 128KiB: A bufs [0,64K) (2 x [256][64] bf16), B bufs [64K,128K).
// Stage: linear dest via global_load_lds; source col pre-XOR'd by
// ((row&7)<<4); ds_read applies the same XOR (rule #21 both-sides).
// Stage order per kt: Ah0,Bh0,Ah1,Bh1, one half per phase, 4-phase lead
// -> uniform vmcnt(4) per phase (2 halves in flight); tail drains 2->0.
// ---------------------------------------------------------------------------
#define VMW(N) asm volatile("s_waitcnt vmcnt(" #N ")" ::: "memory")
#define BAR()  __builtin_amdgcn_s_barrier()
#define PRI1() __builtin_amdgcn_s_setprio(1)
#define PRI0() __builtin_amdgcn_s_setprio(0)

#define STAGE_HALF(SRC, LDSOFF, BUF, HALF, KT)                                  \
  { _Pragma("unroll")                                                           \
    for (int i_ = 0; i_ < 2; ++i_) {                                            \
      __builtin_amdgcn_global_load_lds(                                         \
        (const __attribute__((address_space(1))) void*)                         \
            ((SRC) + (size_t)((HALF)*128 + i_*64)*4096 + (size_t)(KT)*128),     \
        (__attribute__((address_space(3))) void*)                               \
            (ldsc + (LDSOFF) + (BUF)*32768 + (HALF)*16384 + i_*8192 + t16),     \
        16, 0, 0);                                                              \
    } }

#define LDA4(D, BUF, RBASE)                                                     \
  { _Pragma("unroll")                                                           \
    for (int i_ = 0; i_ < 4; ++i_) {                                            \
      const char* p_ = ldsc + (BUF)*32768 + ((RBASE) + i_*16 + lr)*128;         \
      D[i_][0] = *(const bf16x8*)(p_ + kb0);                                    \
      D[i_][1] = *(const bf16x8*)(p_ + kb1);                                    \
    } }

#define LDB2(D, BUF, RBASE)                                                     \
  { _Pragma("unroll")                                                           \
    for (int j_ = 0; j_ < 2; ++j_) {                                            \
      const char* p_ = ldsc + 65536 + (BUF)*32768 + ((RBASE) + j_*16 + lr)*128; \
      D[j_][0] = *(const bf16x8*)(p_ + kb0);                                    \
      D[j_][1] = *(const bf16x8*)(p_ + kb1);                                    \
    } }

#define MF16(IOFF, JOFF, AF, BF)                                                \
  { _Pragma("unroll")                                                           \
    for (int i_ = 0; i_ < 4; ++i_)                                              \
      { _Pragma("unroll")                                                       \
        for (int j_ = 0; j_ < 2; ++j_)                                          \
          { _Pragma("unroll")                                                   \
            for (int k_ = 0; k_ < 2; ++k_)                                      \
              acc[(IOFF)+i_][(JOFF)+j_] =                                       \
                __builtin_amdgcn_mfma_f32_16x16x32_bf16(                        \
                  AF[i_][k_], BF[j_][k_], acc[(IOFF)+i_][(JOFF)+j_], 0, 0, 0);  \
          } } }

__global__ __launch_bounds__(512, 2)
void gemm_kernel(const __bf16* __restrict__ Abf,
                 const __bf16* __restrict__ Bbf,
                 const int* __restrict__ idx,
                 const float* __restrict__ sW,
                 const float* __restrict__ g,
                 const float* __restrict__ hiddens,
                 float* __restrict__ rownorm,
                 float* __restrict__ out) {
  __shared__ __bf16 lds[65536];        // 128 KiB
  char* ldsc = (char*)lds;

  const int bid = blockIdx.x;
  const int mt = bid >> 2, nt = bid & 3;     // 64 M-tiles x 4 N-tiles
  const int m0 = mt * 256, e0 = nt * 256;
  const int tid = threadIdx.x;
  const int lane = tid & 63, wid = tid >> 6;
  const int wr = wid >> 2, wc = wid & 3;     // 2 x 4 wave grid, 128x64/wave
  const int lr = lane & 15, lg = lane >> 4;

  // staging constants: thread covers 16B at linear dest t16; source col
  // pre-swizzled so linear gload_lds produces the swizzled LDS image.
  const int t16  = tid * 16;
  const int colb = t16 & 127;
  const int r_lo = t16 >> 7;                 // row within 8KB chunk (0..63)
  const int scol = colb ^ ((r_lo & 7) << 4);
  const char* Asrc = (const char*)Abf + (size_t)(m0 + r_lo) * 4096 + scol;
  const char* Bsrc = (const char*)Bbf + (size_t)(e0 + r_lo) * 4096 + scol;

  // ds_read swizzled k-offsets (row&7 == lr&7 for all frag rows)
  const int key = (lr & 7) << 4;
  const int kb0 = (lg * 16) ^ key;
  const int kb1 = (64 + lg * 16) ^ key;

  f32x4 acc[8][4] = {};
  bf16x8 aLo[4][2], aHi[4][2], bLo[2][2], bHi[2][2];

  // Prologue: stage kt0 (all 4 halves) into buf0; wait to 4 (Ah0,Bh0 landed).
  STAGE_HALF(Asrc, 0,     0, 0, 0);
  STAGE_HALF(Bsrc, 65536, 0, 0, 0);
  STAGE_HALF(Asrc, 0,     0, 1, 0);
  STAGE_HALF(Bsrc, 65536, 0, 1, 0);
  VMW(4);
  BAR();

  for (int n = 0; n < NT - 1; ++n) {
    const int buf = n & 1, sbuf = buf ^ 1;
    // phase 0: consume Ah0+Bh0; stage next Ah0
    LDA4(aLo, buf, wr * 64);
    LDB2(bLo, buf, wc * 32);
    STAGE_HALF(Asrc, 0, sbuf, 0, n + 1);
    VMW(4); BAR(); PRI1(); MF16(0, 0, aLo, bLo); PRI0(); BAR();
    // phase 1: consume Ah1; stage next Bh0
    LDA4(aHi, buf, wr * 64 + 128);
    STAGE_HALF(Bsrc, 65536, sbuf, 0, n + 1);
    VMW(4); BAR(); PRI1(); MF16(4, 0, aHi, bLo); PRI0(); BAR();
    // phase 2: consume Bh1; stage next Ah1
    LDB2(bHi, buf, wc * 32 + 128);
    STAGE_HALF(Asrc, 0, sbuf, 1, n + 1);
    VMW(4); BAR(); PRI1(); MF16(0, 2, aLo, bHi); PRI0(); BAR();
    // phase 3: reuse regs; stage next Bh1
    STAGE_HALF(Bsrc, 65536, sbuf, 1, n + 1);
    VMW(4); BAR(); PRI1(); MF16(4, 2, aHi, bHi); PRI0(); BAR();
  }
  // Final kt (buf 1): no stages; drain 2 -> 0.
  {
    const int buf = (NT - 1) & 1;
    LDA4(aLo, buf, wr * 64);
    LDB2(bLo, buf, wc * 32);
    VMW(2); BAR(); PRI1(); MF16(0, 0, aLo, bLo); PRI0(); BAR();
    LDA4(aHi, buf, wr * 64 + 128);
    VMW(0); BAR(); PRI1(); MF16(4, 0, aHi, bLo); PRI0(); BAR();
    LDB2(bHi, buf, wc * 32 + 128);
    BAR(); PRI1(); MF16(0, 2, aLo, bHi); PRI0(); BAR();
    PRI1(); MF16(4, 2, aHi, bHi); PRI0();
  }

  // Epilogue: bias + relu + gate + residual + scatter + norm partials.
  // C/D frag layout (m89): lane holds C[(lane>>4)*4 + r][lane&15].
#pragma unroll
  for (int i = 0; i < 8; ++i) {
    const int mrow = m0 + (i & 3) * 16 + wr * 64 + (i >> 2) * 128;
#pragma unroll
    for (int r = 0; r < 4; ++r) {
      int m = mrow + lg * 4 + r;
      int b = m >> 9;
      int rowidx = idx[m & (Kk - 1)];
      size_t base = ((size_t)(b * Nn + rowidx)) * Dd;
      float gg = g[m];
      float part = 0.f;
#pragma unroll
      for (int j = 0; j < 4; ++j) {
        int e = e0 + (j & 1) * 16 + wc * 32 + (j >> 1) * 128 + lr;
        float ht = acc[i][j][r] + sW[b * Nn + e];
        ht = fmaxf(ht, 0.f);
        float v = hiddens[base + e] + gg * ht;
        out[base + e] = v;
        part += v * v;
      }
      part += __shfl_xor(part, 1);
      part += __shfl_xor(part, 2);
      part += __shfl_xor(part, 4);
      part += __shfl_xor(part, 8);
      if (lr == 0) atomicAdd(&rownorm[m], part);
    }
  }
}

// --- rescale updated rows by rsqrt(max(rownorm, eps))
__global__ void norm_kernel(const int* __restrict__ idx,
                            const float* __restrict__ rownorm,
                            float* __restrict__ out) {
  int m = blockIdx.x;
  int b = m >> 9;
  int rowidx = idx[m & (Kk - 1)];
  float nr = fmaxf(rownorm[m], 1e-12f);
  float y = rsqrtf(nr);
  y = y * (1.5f - 0.5f * nr * y * y);   // Newton step for fp32 accuracy
  f32x4* p = (f32x4*)(out + ((size_t)(b * Nn + rowidx)) * Dd);
  f32x4 v = p[threadIdx.x];
  v[0] *= y; v[1] *= y; v[2] *= y; v[3] *= y;
  p[threadIdx.x] = v;
}

extern "C" void kernel_launch(void* const* d_in, const int* in_sizes, int n_in,
                              void* d_out, int out_size, void* d_ws, size_t ws_size,
                              hipStream_t stream) {
  const float* s       = (const float*)d_in[0];
  const float* hiddens = (const float*)d_in[1];
  const float* keys    = (const float*)d_in[2];
  const float* U       = (const float*)d_in[3];
  const float* V       = (const float*)d_in[4];
  const float* W       = (const float*)d_in[5];
  const int*   idx     = (const int*)d_in[6];
  float* out = (float*)d_out;

  char* ws = (char*)d_ws;
  __bf16* Abf   = (__bf16*)(ws + WS_ABF);
  __bf16* Bbf   = (__bf16*)(ws + WS_BBF);
  float*  g     = (float*)(ws + WS_G);
  float*  sW    = (float*)(ws + WS_SW);
  float*  rnorm = (float*)(ws + WS_RN);
  int*    mask  = (int*)(ws + WS_MASK);

  hipMemsetAsync(rnorm, 0, Mm * sizeof(float), stream);
  mask_kernel<<<1, Nn, 0, stream>>>(idx, mask);
  prep_b_kernel<<<1024, 256, 0, stream>>>(U, V, Bbf);
  sw_kernel<<<Nn / 4, 256, 0, stream>>>(s, W, sW);
  prep_rows_kernel<<<Bb * Nn, 256, 0, stream>>>(s, hiddens, keys, mask, Abf, g, out);
  gemm_kernel<<<(Mm / 256) * (Nn / 256), 512, 0, stream>>>(
      Abf, Bbf, idx, sW, g, hiddens, rnorm, out);
  norm_kernel<<<Mm, 256, 0, stream>>>(idx, rnorm, out);
}